// Round 12
// baseline (103.111 us; speedup 1.0000x reference)
//
#include <hip/hip_runtime.h>
#include <hip/hip_bf16.h>

#define LEAKY 0.2f
#define B_TOT 8192
#define N_TOT 2048
#define D_TOT 128
#define BM 16

typedef float f32x4 __attribute__((ext_vector_type(4)));
typedef short bf16x8 __attribute__((ext_vector_type(8)));
typedef unsigned short u16x8 __attribute__((ext_vector_type(8)));

static __device__ __forceinline__ unsigned short f2bf(float x) {
    return __builtin_bit_cast(unsigned short, __float2bfloat16(x));
}

// ============ Launch A: self-sufficient q + bitonic sort + tables ============
// 33 blocks x 512 threads. Every block computes all q and sorts identically
// (deterministic, so no cross-block exchange). Blocks 0-31: chunk prefix
// tables P1/P2/T1/T2 for ranks [64b,64b+64). Block 32: scalar suffix/prefix
// scans + sortedq.
__global__ __launch_bounds__(512) void sort_scan_kernel(const float* __restrict__ disease,
                                                        const float* __restrict__ ak,
                                                        float* __restrict__ sortedq,
                                                        float* __restrict__ P1,
                                                        float* __restrict__ P2,
                                                        float* __restrict__ T1,
                                                        float* __restrict__ T2,
                                                        float* __restrict__ S1suf,
                                                        float* __restrict__ S2pre) {
    __shared__ float key[N_TOT];
    __shared__ int   idx[N_TOT];
    __shared__ float seg1[4][128], seg2[4][128];
    __shared__ float w1[8], w2[8];
    __shared__ float e1l[64], e2l[64];
    __shared__ int   perm_s[64];

    const int tid = threadIdx.x;
    const int b = blockIdx.x;

    // ---- q-dots: half-wave (32 lanes) per row, float4 coalesced ----
    const int hw = tid >> 5, hl = tid & 31;      // 16 half-waves
    const float4 av = *(const float4*)(ak + D_TOT + hl * 4);
    for (int i = tid; i < N_TOT; i += 512) idx[i] = i;
    for (int r = hw; r < N_TOT; r += 16) {
        const float4 v = *(const float4*)(disease + (size_t)r * D_TOT + hl * 4);
        float s = v.x * av.x + v.y * av.y + v.z * av.z + v.w * av.w;
        s += __shfl_xor(s, 16); s += __shfl_xor(s, 8); s += __shfl_xor(s, 4);
        s += __shfl_xor(s, 2);  s += __shfl_xor(s, 1);
        if (hl == 0) key[r] = s;
    }
    __syncthreads();

    // ---- bitonic sort ascending (key, idx), deterministic ----
    for (int k = 2; k <= N_TOT; k <<= 1) {
        for (int j = k >> 1; j > 0; j >>= 1) {
            for (int i = tid; i < N_TOT; i += 512) {
                const int ixj = i ^ j;
                if (ixj > i) {
                    const bool up = ((i & k) == 0);
                    const float ki = key[i], kj = key[ixj];
                    const bool sw = up ? (ki > kj) : (ki < kj);
                    if (sw) {
                        key[i] = kj; key[ixj] = ki;
                        const int t = idx[i]; idx[i] = idx[ixj]; idx[ixj] = t;
                    }
                }
            }
            __syncthreads();
        }
    }

    if (b < 32) {
        // ---- chunk prefix tables (proven R9 structure) ----
        const int r0 = b * 64;
        if (tid < 64) {
            perm_s[tid] = idx[r0 + tid];
            const float kq = key[r0 + tid];
            e1l[tid] = __expf(kq);
            e2l[tid] = __expf(LEAKY * kq);
        }
        __syncthreads();
        const int col = tid & 127, seg = tid >> 7;   // 4 segs x 16 ranks
        float d[16];
        #pragma unroll
        for (int jj = 0; jj < 16; ++jj)
            d[jj] = disease[(size_t)perm_s[seg * 16 + jj] * D_TOT + col];
        float s1 = 0.f, s2 = 0.f;
        #pragma unroll
        for (int jj = 0; jj < 16; ++jj) {
            s1 += e1l[seg * 16 + jj] * d[jj];
            s2 += e2l[seg * 16 + jj] * d[jj];
        }
        seg1[seg][col] = s1; seg2[seg][col] = s2;
        __syncthreads();
        float run1 = 0.f, run2 = 0.f;
        for (int s = 0; s < seg; ++s) { run1 += seg1[s][col]; run2 += seg2[s][col]; }
        #pragma unroll
        for (int jj = 0; jj < 16; ++jj) {
            const int j = seg * 16 + jj;
            P1[(size_t)(r0 + j) * D_TOT + col] = run1;
            P2[(size_t)(r0 + j) * D_TOT + col] = run2;
            run1 += e1l[j] * d[jj];
            run2 += e2l[j] * d[jj];
        }
        if (seg == 3) { T1[b * 128 + col] = run1; T2[b * 128 + col] = run2; }
    } else {
        // ---- scalar suffix/prefix scans (proven R9 structure) + sortedq ----
        const int lane = tid & 63, wv = tid >> 6;
        float a1[4], a2[4], s1[4], s2[4];
        #pragma unroll
        for (int i = 0; i < 4; ++i) {
            const float kq = key[tid * 4 + i];
            a1[i] = __expf(kq);
            a2[i] = __expf(LEAKY * kq);
        }
        float r1 = 0.f, r2 = 0.f;
        #pragma unroll
        for (int i = 0; i < 4; ++i) { r1 += a1[i]; s1[i] = r1; r2 += a2[i]; s2[i] = r2; }
        float i1 = r1, i2 = r2;
        #pragma unroll
        for (int off = 1; off < 64; off <<= 1) {
            const float v1 = __shfl_up(i1, off);
            const float v2 = __shfl_up(i2, off);
            if (lane >= off) { i1 += v1; i2 += v2; }
        }
        if (lane == 63) { w1[wv] = i1; w2[wv] = i2; }
        __syncthreads();
        float o1 = 0.f, o2 = 0.f, tot1 = 0.f, tot2 = 0.f;
        #pragma unroll
        for (int w = 0; w < 8; ++w) {
            tot1 += w1[w]; tot2 += w2[w];
            if (w < wv) { o1 += w1[w]; o2 += w2[w]; }
        }
        const float base1 = o1 + i1 - r1;   // exclusive prefix before elem tid*4
        const float base2 = o2 + i2 - r2;
        #pragma unroll
        for (int i = 0; i < 4; ++i) {
            const float EP1 = base1 + (i ? s1[i - 1] : 0.f);
            const float EP2 = base2 + (i ? s2[i - 1] : 0.f);
            S1suf[tid * 4 + i] = tot1 - EP1;   // sum over ranks >= idx
            S2pre[tid * 4 + i] = EP2;          // sum over ranks <  idx
        }
        if (tid == 0) { S1suf[N_TOT] = 0.f; S2pre[N_TOT] = tot2; }
        for (int i = tid; i < N_TOT; i += 512) sortedq[i] = key[i];
    }
}

// ============ Launch B: per-row threshold lookup (R9 verbatim, proven) ============
__global__ __launch_bounds__(256) void gat_ps(const float* __restrict__ patient,
                                              const float* __restrict__ ak,
                                              const float* __restrict__ sortedq,
                                              const float* __restrict__ P1,
                                              const float* __restrict__ P2,
                                              const float* __restrict__ T1,
                                              const float* __restrict__ T2,
                                              const float* __restrict__ S1suf,
                                              const float* __restrict__ S2pre,
                                              float* __restrict__ out) {
    __shared__ float sq[N_TOT];
    __shared__ float suf1[33][128];
    __shared__ float pre2[33][128];
    __shared__ float a_s[D_TOT];
    __shared__ float p_s[32];
    __shared__ float e1_s[32], e2_s[32], inv_s[32];
    __shared__ int   c_s[32];
    const int tid = threadIdx.x;
    const int b0 = blockIdx.x * 32;

    for (int i = tid; i < N_TOT; i += 256) sq[i] = sortedq[i];
    if (tid < D_TOT) a_s[tid] = ak[tid];

    if (tid < 128) {
        float t[32];
        #pragma unroll
        for (int b = 0; b < 32; ++b) t[b] = T1[b * 128 + tid];
        float r = 0.f;
        suf1[32][tid] = 0.f;
        #pragma unroll
        for (int b = 31; b >= 0; --b) { r += t[b]; suf1[b][tid] = r; }
    } else {
        const int col = tid - 128;
        float t[32];
        #pragma unroll
        for (int b = 0; b < 32; ++b) t[b] = T2[b * 128 + col];
        float r = 0.f;
        #pragma unroll
        for (int b = 0; b < 32; ++b) { pre2[b][col] = r; r += t[b]; }
        pre2[32][col] = r;
    }
    __syncthreads();

    const int wave = tid >> 6, lane = tid & 63;
    #pragma unroll
    for (int rr = 0; rr < 8; ++rr) {
        const int row = wave * 8 + rr;
        const float* pr = patient + (size_t)(b0 + row) * D_TOT;
        float s = pr[lane] * a_s[lane] + pr[lane + 64] * a_s[lane + 64];
        #pragma unroll
        for (int off = 32; off; off >>= 1) s += __shfl_xor(s, off);
        if (lane == 0) p_s[row] = s;
    }
    __syncthreads();

    if (tid < 32) {
        const float pv = p_s[tid];
        const float qmax = sq[N_TOT - 1];
        const float xm = pv + qmax;
        const float m = fmaxf(xm, LEAKY * xm);
        const float E1 = __expf(pv - m);
        const float E2 = __expf(LEAKY * pv - m);
        const float thr = -pv;
        int lo = 0, hi = N_TOT;
        while (lo < hi) {
            int mid = (lo + hi) >> 1;
            if (sq[mid] <= thr) lo = mid + 1; else hi = mid;
        }
        const float S = E1 * S1suf[lo] + E2 * S2pre[lo];
        e1_s[tid] = E1; e2_s[tid] = E2; inv_s[tid] = 1.0f / S; c_s[tid] = lo;
    }
    __syncthreads();

    const int row = tid >> 3;
    const int cb = (tid & 7) * 16;
    const int gr = b0 + row;
    const int c = c_s[row];
    const int bc = c >> 6;
    const float E1 = e1_s[row], E2 = e2_s[row], inv = inv_s[row];
    const bool has = (c < N_TOT);

    #pragma unroll
    for (int i = 0; i < 4; ++i) {
        const int col = cb + i * 4;
        float4 p1 = make_float4(0.f, 0.f, 0.f, 0.f);
        float4 p2 = make_float4(0.f, 0.f, 0.f, 0.f);
        if (has) {
            p1 = *(const float4*)&P1[(size_t)c * D_TOT + col];
            p2 = *(const float4*)&P2[(size_t)c * D_TOT + col];
        }
        const float4 pat = *(const float4*)&patient[(size_t)gr * D_TOT + col];
        float4 o;
        o.x = pat.x + (E1 * (suf1[bc][col + 0] - p1.x) + E2 * (pre2[bc][col + 0] + p2.x)) * inv;
        o.y = pat.y + (E1 * (suf1[bc][col + 1] - p1.y) + E2 * (pre2[bc][col + 1] + p2.y)) * inv;
        o.z = pat.z + (E1 * (suf1[bc][col + 2] - p1.z) + E2 * (pre2[bc][col + 2] + p2.z)) * inv;
        o.w = pat.w + (E1 * (suf1[bc][col + 3] - p1.w) + E2 * (pre2[bc][col + 3] + p2.w)) * inv;
        *(float4*)&out[(size_t)gr * D_TOT + col] = o;
    }
}

// ============ MID fallback: R11 MFMA path (26.5 µs proven) ============
__global__ __launch_bounds__(256) void prep_kernel(const float* __restrict__ disease,
                                                   const float* __restrict__ ak,
                                                   float* __restrict__ q,
                                                   uint4* __restrict__ DnTf) {
    __shared__ float tile[32][129];
    __shared__ float a_s[D_TOT];
    const int tid = threadIdx.x;
    const int b = blockIdx.x;
    const int r0 = b * 32;
    if (tid < D_TOT) a_s[tid] = ak[D_TOT + tid];
    #pragma unroll
    for (int t = 0; t < 4; ++t) {
        int idx = tid + t * 256;
        int row = idx >> 5;
        int cv = (idx & 31) * 4;
        float4 v = *(const float4*)(disease + (size_t)(r0 + row) * D_TOT + cv);
        tile[row][cv] = v.x; tile[row][cv + 1] = v.y;
        tile[row][cv + 2] = v.z; tile[row][cv + 3] = v.w;
    }
    __syncthreads();
    const int wave = tid >> 6, lane = tid & 63;
    #pragma unroll
    for (int rr = 0; rr < 8; ++rr) {
        int r = wave * 8 + rr;
        float s = tile[r][lane] * a_s[lane] + tile[r][lane + 64] * a_s[lane + 64];
        #pragma unroll
        for (int off = 32; off; off >>= 1) s += __shfl_xor(s, off);
        if (lane == 0) q[r0 + r] = s;
    }
    #pragma unroll
    for (int h = 0; h < 2; ++h) {
        const int c  = tid + h * 256;
        const int kg = c >> 7;
        const int col = c & 127;
        const int ct = col >> 4, cl = col & 15;
        unsigned u[4];
        #pragma unroll
        for (int jj = 0; jj < 4; ++jj) {
            unsigned lo = f2bf(tile[kg * 8 + 2 * jj][col]);
            unsigned hi = f2bf(tile[kg * 8 + 2 * jj + 1][col]);
            u[jj] = lo | (hi << 16);
        }
        DnTf[((size_t)b * 8 + ct) * 64 + kg * 16 + cl] = make_uint4(u[0], u[1], u[2], u[3]);
    }
}

__global__ __launch_bounds__(1024, 8) void gat_mfma(const float* __restrict__ patient,
                                                    const float* __restrict__ ak,
                                                    const float* __restrict__ q,
                                                    const uint4* __restrict__ DnTf,
                                                    float* __restrict__ out) {
    __shared__ __align__(16) float eq1_s[N_TOT];
    __shared__ __align__(16) float eq2_s[N_TOT];
    __shared__ float red_s[7][2][1024];
    __shared__ float a_s[D_TOT];
    __shared__ float p_s[BM], E1_s[BM], E2_s[BM], S_s[BM];
    __shared__ float red16[16];
    const int tid  = threadIdx.x;
    const int wave = tid >> 6;
    const int lane = tid & 63;
    const int b0   = blockIdx.x * BM;
    if (tid < D_TOT) a_s[tid] = ak[tid];
    __syncthreads();
    float mx = -1e30f;
    for (int i = tid; i < N_TOT; i += 1024) {
        float qq = q[i];
        eq1_s[i] = __expf(qq);
        eq2_s[i] = __expf(LEAKY * qq);
        mx = fmaxf(mx, qq);
    }
    #pragma unroll
    for (int off = 32; off; off >>= 1) mx = fmaxf(mx, __shfl_xor(mx, off));
    if (lane == 0) red16[wave] = mx;
    {
        const float* pr = patient + (size_t)(b0 + wave) * D_TOT;
        float s = pr[lane] * a_s[lane] + pr[lane + 64] * a_s[lane + 64];
        #pragma unroll
        for (int off = 32; off; off >>= 1) s += __shfl_xor(s, off);
        if (lane == 0) p_s[wave] = s;
    }
    __syncthreads();
    if (tid < BM) {
        float qmax = red16[0];
        #pragma unroll
        for (int i = 1; i < 16; ++i) qmax = fmaxf(qmax, red16[i]);
        const float pv = p_s[tid];
        const float xm = pv + qmax;
        const float m = fmaxf(xm, LEAKY * xm);
        E1_s[tid] = __expf(pv - m);
        E2_s[tid] = __expf(LEAKY * pv - m);
    }
    __syncthreads();
    {
        const float E1 = E1_s[wave], E2 = E2_s[wave];
        float s = 0.f;
        for (int n = lane; n < N_TOT; n += 64)
            s += fmaxf(E1 * eq1_s[n], E2 * eq2_s[n]);
        #pragma unroll
        for (int off = 32; off; off >>= 1) s += __shfl_xor(s, off);
        if (lane == 0) S_s[wave] = s;
    }
    __syncthreads();
    const int cl = lane & 15;
    const int kg = lane >> 4;
    const int cw = wave & 1;
    const int kq = wave >> 1;
    const float E1A = E1_s[cl], E2A = E2_s[cl];
    const uint4* fbase = DnTf + (size_t)(cw * 4) * 64 + lane;
    f32x4 acc[4] = {};
    for (int kt = kq * 8; kt < kq * 8 + 8; ++kt) {
        const uint4* fp = fbase + (size_t)kt * 512;
        const uint4 b0v = fp[0];
        const uint4 b1v = fp[64];
        const uint4 b2v = fp[128];
        const uint4 b3v = fp[192];
        const int gk = kt * 32 + kg * 8;
        u16x8 aw;
        {
            const float4 e1 = *(const float4*)&eq1_s[gk];
            const float4 e2 = *(const float4*)&eq2_s[gk];
            aw[0] = f2bf(fmaxf(E1A * e1.x, E2A * e2.x));
            aw[1] = f2bf(fmaxf(E1A * e1.y, E2A * e2.y));
            aw[2] = f2bf(fmaxf(E1A * e1.z, E2A * e2.z));
            aw[3] = f2bf(fmaxf(E1A * e1.w, E2A * e2.w));
        }
        {
            const float4 e1 = *(const float4*)&eq1_s[gk + 4];
            const float4 e2 = *(const float4*)&eq2_s[gk + 4];
            aw[4] = f2bf(fmaxf(E1A * e1.x, E2A * e2.x));
            aw[5] = f2bf(fmaxf(E1A * e1.y, E2A * e2.y));
            aw[6] = f2bf(fmaxf(E1A * e1.z, E2A * e2.z));
            aw[7] = f2bf(fmaxf(E1A * e1.w, E2A * e2.w));
        }
        const bf16x8 a0 = __builtin_bit_cast(bf16x8, aw);
        acc[0] = __builtin_amdgcn_mfma_f32_16x16x32_bf16(a0, __builtin_bit_cast(bf16x8, b0v), acc[0], 0, 0, 0);
        acc[1] = __builtin_amdgcn_mfma_f32_16x16x32_bf16(a0, __builtin_bit_cast(bf16x8, b1v), acc[1], 0, 0, 0);
        acc[2] = __builtin_amdgcn_mfma_f32_16x16x32_bf16(a0, __builtin_bit_cast(bf16x8, b2v), acc[2], 0, 0, 0);
        acc[3] = __builtin_amdgcn_mfma_f32_16x16x32_bf16(a0, __builtin_bit_cast(bf16x8, b3v), acc[3], 0, 0, 0);
    }
    __syncthreads();
    if (kq > 0) {
        float* rb = &red_s[kq - 1][cw][0];
        #pragma unroll
        for (int t = 0; t < 4; ++t)
            #pragma unroll
            for (int i = 0; i < 4; ++i)
                rb[t * 256 + (kg * 4 + i) * 16 + cl] = acc[t][i];
    }
    __syncthreads();
    if (kq == 0) {
        #pragma unroll
        for (int t = 0; t < 4; ++t)
            #pragma unroll
            for (int i = 0; i < 4; ++i) {
                const int idx = t * 256 + (kg * 4 + i) * 16 + cl;
                float s = acc[t][i];
                #pragma unroll
                for (int j = 0; j < 7; ++j) s += red_s[j][cw][idx];
                acc[t][i] = s;
            }
        float inv[4];
        #pragma unroll
        for (int i = 0; i < 4; ++i) inv[i] = 1.0f / S_s[kg * 4 + i];
        #pragma unroll
        for (int t = 0; t < 4; ++t)
            #pragma unroll
            for (int i = 0; i < 4; ++i) {
                const int row = b0 + kg * 4 + i;
                const int col = cw * 64 + t * 16 + cl;
                out[(size_t)row * D_TOT + col] =
                    patient[(size_t)row * D_TOT + col] + acc[t][i] * inv[i];
            }
    }
}

// ============ tiny fallback (round-1) ============
__global__ __launch_bounds__(256) void pq_fb(const float* __restrict__ patient,
                                             const float* __restrict__ disease,
                                             const float* __restrict__ ak,
                                             float* __restrict__ p,
                                             float* __restrict__ q) {
    int gid  = blockIdx.x * blockDim.x + threadIdx.x;
    int wid  = gid >> 6;
    int lane = gid & 63;
    const float* src;
    const float* a;
    float* dst;
    if (wid < B_TOT) {
        src = patient + (size_t)wid * D_TOT; a = ak; dst = p + wid;
    } else {
        src = disease + (size_t)(wid - B_TOT) * D_TOT; a = ak + D_TOT; dst = q + (wid - B_TOT);
    }
    float s = src[lane] * a[lane] + src[lane + 64] * a[lane + 64];
    #pragma unroll
    for (int off = 32; off; off >>= 1) s += __shfl_xor(s, off);
    if (lane == 0) *dst = s;
}

#define FBP 16
#define FNT 256
__global__ __launch_bounds__(256) void gat_fb(const float* __restrict__ patient,
                                              const float* __restrict__ disease,
                                              const float* __restrict__ p,
                                              const float* __restrict__ q,
                                              float* __restrict__ out) {
    __shared__ float q_s[N_TOT];
    __shared__ float w_s[FBP][FNT];
    __shared__ float m_s[FBP], S_s[FBP], pp_s[FBP];
    const int tid = threadIdx.x;
    const int b0  = blockIdx.x * FBP;
    for (int i = tid; i < N_TOT; i += 256) q_s[i] = q[i];
    if (tid < FBP) pp_s[tid] = p[b0 + tid];
    __syncthreads();
    const int wave = tid >> 6, lane = tid & 63;
    for (int pi = wave * 4; pi < wave * 4 + 4; ++pi) {
        float pp = pp_s[pi];
        float mx = -1e30f;
        for (int n = lane; n < N_TOT; n += 64) {
            float x = pp + q_s[n]; x = x > 0.0f ? x : LEAKY * x; mx = fmaxf(mx, x);
        }
        #pragma unroll
        for (int off = 32; off; off >>= 1) mx = fmaxf(mx, __shfl_xor(mx, off));
        float sum = 0.0f;
        for (int n = lane; n < N_TOT; n += 64) {
            float x = pp + q_s[n]; x = x > 0.0f ? x : LEAKY * x; sum += __expf(x - mx);
        }
        #pragma unroll
        for (int off = 32; off; off >>= 1) sum += __shfl_xor(sum, off);
        if (lane == 0) { m_s[pi] = mx; S_s[pi] = sum; }
    }
    __syncthreads();
    const int d2 = tid & 31;
    const int pg = tid >> 5;
    const int p0 = 2 * pg, p1 = 2 * pg + 1;
    float4 acc0 = make_float4(0.f, 0.f, 0.f, 0.f);
    float4 acc1 = make_float4(0.f, 0.f, 0.f, 0.f);
    for (int n0 = 0; n0 < N_TOT; n0 += FNT) {
        __syncthreads();
        for (int i = tid; i < FBP * FNT; i += 256) {
            int pi = i >> 8;
            int nt = i & (FNT - 1);
            float x = pp_s[pi] + q_s[n0 + nt];
            x = x > 0.0f ? x : LEAKY * x;
            w_s[pi][nt] = __expf(x - m_s[pi]);
        }
        __syncthreads();
        const float* drow = disease + (size_t)n0 * D_TOT + d2 * 4;
        #pragma unroll 4
        for (int nt = 0; nt < FNT; ++nt) {
            float4 dv = *reinterpret_cast<const float4*>(drow + (size_t)nt * D_TOT);
            float w0 = w_s[p0][nt];
            float w1 = w_s[p1][nt];
            acc0.x += w0 * dv.x; acc0.y += w0 * dv.y; acc0.z += w0 * dv.z; acc0.w += w0 * dv.w;
            acc1.x += w1 * dv.x; acc1.y += w1 * dv.y; acc1.z += w1 * dv.z; acc1.w += w1 * dv.w;
        }
    }
    const float inv0 = 1.0f / S_s[p0];
    const float inv1 = 1.0f / S_s[p1];
    {
        size_t off = (size_t)(b0 + p0) * D_TOT + d2 * 4;
        float4 pf = *reinterpret_cast<const float4*>(patient + off);
        float4 o;
        o.x = pf.x + acc0.x * inv0; o.y = pf.y + acc0.y * inv0;
        o.z = pf.z + acc0.z * inv0; o.w = pf.w + acc0.w * inv0;
        *reinterpret_cast<float4*>(reinterpret_cast<float*>(out) + off) = o;
    }
    {
        size_t off = (size_t)(b0 + p1) * D_TOT + d2 * 4;
        float4 pf = *reinterpret_cast<const float4*>(patient + off);
        float4 o;
        o.x = pf.x + acc1.x * inv1; o.y = pf.y + acc1.y * inv1;
        o.z = pf.z + acc1.z * inv1; o.w = pf.w + acc1.w * inv1;
        *reinterpret_cast<float4*>(reinterpret_cast<float*>(out) + off) = o;
    }
}

extern "C" void kernel_launch(void* const* d_in, const int* in_sizes, int n_in,
                              void* d_out, int out_size, void* d_ws, size_t ws_size,
                              hipStream_t stream) {
    const float* patient = (const float*)d_in[0];   // 8192 x 128
    const float* disease = (const float*)d_in[1];   // 2048 x 128
    const float* ak      = (const float*)d_in[2];   // 256
    float* out = (float*)d_out;
    char* w = (char*)d_ws;

    const size_t oP1 = 0;                  // [2048][128] f32 = 1 MB
    const size_t oP2 = 1048576;            // 1 MB
    const size_t oT1 = 2097152;            // 16 KB
    const size_t oT2 = 2113536;            // 16 KB
    const size_t oS1 = 2129920;            // [2049]
    const size_t oS2 = 2138368;
    const size_t oSQ = 2146816;            // sortedq
    const size_t need_fast = 2220544;
    const size_t need_mid  = (size_t)512 * 1024 + 8192;

    if (ws_size >= need_fast) {
        float* P1 = (float*)(w + oP1);
        float* P2 = (float*)(w + oP2);
        float* T1 = (float*)(w + oT1);
        float* T2 = (float*)(w + oT2);
        float* S1 = (float*)(w + oS1);
        float* S2 = (float*)(w + oS2);
        float* sq = (float*)(w + oSQ);
        sort_scan_kernel<<<33, 512, 0, stream>>>(disease, ak, sq, P1, P2, T1, T2, S1, S2);
        gat_ps<<<B_TOT / 32, 256, 0, stream>>>(patient, ak, sq, P1, P2, T1, T2, S1, S2, out);
    } else if (ws_size >= need_mid) {
        uint4* DnTf = (uint4*)d_ws;
        float* q    = (float*)(w + 512 * 1024);
        prep_kernel<<<N_TOT / 32, 256, 0, stream>>>(disease, ak, q, DnTf);
        gat_mfma<<<B_TOT / BM, 1024, 0, stream>>>(patient, ak, q, DnTf, out);
    } else {
        float* p = (float*)d_ws;
        float* q = p + B_TOT;
        pq_fb<<<(B_TOT + N_TOT) / 4, 256, 0, stream>>>(patient, disease, ak, p, q);
        gat_fb<<<B_TOT / FBP, 256, 0, stream>>>(patient, disease, p, q, out);
    }
}

// Round 13
// 78.251 us; speedup vs baseline: 1.3177x; 1.3177x over previous
//
#include <hip/hip_runtime.h>

#define LEAKY 0.2f
#define B_TOT 8192
#define N_TOT 2048
#define D_TOT 128

// ============ Launch A: per-block q-dots + rank-by-count -> sortedq, perm ============
// 64 blocks x 512 threads. Each block computes ALL q itself (no dependency on a
// prior launch), then ranks its 32 owned elements and scatters.
__global__ __launch_bounds__(512) void qrank_kernel(const float* __restrict__ disease,
                                                    const float* __restrict__ ak,
                                                    float* __restrict__ sortedq,
                                                    int* __restrict__ perm) {
    __shared__ float q_s[N_TOT];
    __shared__ float a_s[D_TOT];
    const int tid = threadIdx.x;
    if (tid < D_TOT) a_s[tid] = ak[D_TOT + tid];
    __syncthreads();

    // q-dots: half-wave (32 lanes) per row, 4 independent rows in flight
    const int hw = tid >> 5, hl = tid & 31;      // 16 half-waves
    const float4 av = *(const float4*)(a_s + hl * 4);
    for (int r = hw; r < N_TOT; r += 64) {
        float s[4];
        #pragma unroll
        for (int u = 0; u < 4; ++u) {
            const float4 v = *(const float4*)(disease + (size_t)(r + u * 16) * D_TOT + hl * 4);
            s[u] = v.x * av.x + v.y * av.y + v.z * av.z + v.w * av.w;
        }
        #pragma unroll
        for (int u = 0; u < 4; ++u) {
            s[u] += __shfl_xor(s[u], 16); s[u] += __shfl_xor(s[u], 8);
            s[u] += __shfl_xor(s[u], 4);  s[u] += __shfl_xor(s[u], 2);
            s[u] += __shfl_xor(s[u], 1);
        }
        if (hl == 0) {
            #pragma unroll
            for (int u = 0; u < 4; ++u) q_s[r + u * 16] = s[u];
        }
    }
    __syncthreads();

    // rank: 32 elements/block, 16 threads per element, 128 compares each
    const int kl = tid >> 4, sub = tid & 15;
    const int k = blockIdx.x * 32 + kl;
    const float qk = q_s[k];
    int cnt = 0;
    const int j0 = sub * 128;
    #pragma unroll 8
    for (int j = j0; j < j0 + 128; ++j) {
        const float qj = q_s[j];
        cnt += (qj < qk || (qj == qk && j < k)) ? 1 : 0;
    }
    cnt += __shfl_xor(cnt, 1); cnt += __shfl_xor(cnt, 2);
    cnt += __shfl_xor(cnt, 4); cnt += __shfl_xor(cnt, 8);
    if (sub == 0) { sortedq[cnt] = qk; perm[cnt] = k; }
}

// ============ Launch B: snapshot-stream main ============
// 256 blocks x 1024 threads, 32 patients/block. Descending-q stream of Dn rows
// with 128-wide running sums; snapshots at each patient's threshold.
__global__ __launch_bounds__(1024) void gat_stream(const float* __restrict__ patient,
                                                   const float* __restrict__ disease,
                                                   const float* __restrict__ ak,
                                                   const float* __restrict__ sortedq,
                                                   const int* __restrict__ perm,
                                                   float* __restrict__ out) {
    __shared__ float sq[N_TOT];
    __shared__ float e1l[N_TOT], e2l[N_TOT];
    __shared__ int   perm_l[N_TOT];
    __shared__ unsigned mask[N_TOT];
    __shared__ float snap1[32][128], snap2[32][128];
    __shared__ float sseg1[9][128], sseg2[9][128];
    __shared__ float a_s[D_TOT];
    __shared__ float p_s[32], E1_s[32], E2_s[32], inv_s[32];
    __shared__ int   c_s[32];

    const int tid  = threadIdx.x;
    const int wave = tid >> 6;
    const int lane = tid & 63;
    const int b0   = blockIdx.x * 32;

    // P1: load sorted q / perm, derive e1/e2, zero mask
    for (int i = tid; i < N_TOT; i += 1024) {
        const float s = sortedq[i];
        sq[i]   = s;
        e1l[i]  = __expf(s);
        e2l[i]  = __expf(LEAKY * s);
        perm_l[i] = perm[i];
        mask[i] = 0u;
    }
    if (tid < D_TOT) a_s[tid] = ak[tid];
    __syncthreads();

    // P2: p-dots (16 waves x 2 rows, proven pattern)
    #pragma unroll
    for (int rr = 0; rr < 2; ++rr) {
        const int row = wave * 2 + rr;
        const float* pr = patient + (size_t)(b0 + row) * D_TOT;
        float s = pr[lane] * a_s[lane] + pr[lane + 64] * a_s[lane + 64];
        #pragma unroll
        for (int off = 32; off; off >>= 1) s += __shfl_xor(s, off);
        if (lane == 0) p_s[row] = s;
    }
    __syncthreads();

    // P3: E1/E2/S per row (R11 exact max-trick) + binary search + mask set
    #pragma unroll
    for (int rr = 0; rr < 2; ++rr) {
        const int row = wave * 2 + rr;
        const float pv = p_s[row];
        const float qmax = sq[N_TOT - 1];
        const float xm = pv + qmax;
        const float m = fmaxf(xm, LEAKY * xm);       // row max (leaky monotonic)
        const float E1 = __expf(pv - m);
        const float E2 = __expf(LEAKY * pv - m);
        float s = 0.f;
        for (int n = lane; n < N_TOT; n += 64)
            s += fmaxf(E1 * e1l[n], E2 * e2l[n]);
        #pragma unroll
        for (int off = 32; off; off >>= 1) s += __shfl_xor(s, off);
        if (lane == 0) { E1_s[row] = E1; E2_s[row] = E2; inv_s[row] = 1.0f / s; }
    }
    if (tid < 32) {
        const float thr = -p_s[tid];
        int lo = 0, hi = N_TOT;
        while (lo < hi) {                            // first idx with sq[idx] > thr
            const int mid = (lo + hi) >> 1;
            if (sq[mid] <= thr) lo = mid + 1; else hi = mid;
        }
        c_s[tid] = lo;
        if (lo < N_TOT) atomicOr(&mask[lo], 1u << tid);
    }
    __syncthreads();

    // P4: descending stream, 8 groups x 128 cols, 256 rows each
    {
        const int g = tid >> 7;
        const int col = tid & 127;
        const int jbase = g * 256;
        float run1 = 0.f, run2 = 0.f;
        #pragma unroll 4
        for (int jj = 255; jj >= 0; --jj) {
            const int j = jbase + jj;
            const float d = disease[(size_t)perm_l[j] * D_TOT + col];
            run1 = fmaf(e1l[j], d, run1);
            run2 = fmaf(e2l[j], d, run2);
            unsigned mk = mask[j];
            while (mk) {
                const int r = __ffs(mk) - 1;
                mk &= mk - 1;
                snap1[r][col] = run1;
                snap2[r][col] = run2;
            }
        }
        sseg1[g][col] = run1;
        sseg2[g][col] = run2;
    }
    __syncthreads();

    // P5: in-place suffix over segment totals (rows 0..7), sentinel row 8 = 0
    if (tid < 128) {
        float r1 = 0.f, r2 = 0.f;
        sseg1[8][tid] = 0.f; sseg2[8][tid] = 0.f;
        #pragma unroll
        for (int s = 7; s >= 0; --s) {
            r1 += sseg1[s][tid]; sseg1[s][tid] = r1;
            r2 += sseg2[s][tid]; sseg2[s][tid] = r2;
        }
    }
    __syncthreads();

    // P6: output. row = tid>>5, 4 cols per thread.
    {
        const int row = tid >> 5;
        const int c0 = (tid & 31) * 4;
        const int gr = b0 + row;
        const int c = c_s[row];
        const bool has = (c < N_TOT);
        const int sg1 = has ? ((c >> 8) + 1) : 8;    // segments strictly above
        const float E1 = E1_s[row], E2 = E2_s[row], inv = inv_s[row];
        const float4 pat = *(const float4*)&patient[(size_t)gr * D_TOT + c0];
        float o[4];
        #pragma unroll
        for (int i = 0; i < 4; ++i) {
            const int col = c0 + i;
            const float suf1 = (has ? snap1[row][col] : 0.f) + sseg1[sg1][col];
            const float suf2 = (has ? snap2[row][col] : 0.f) + sseg2[sg1][col];
            const float pre2 = sseg2[0][col] - suf2;
            const float pi = (i == 0) ? pat.x : (i == 1) ? pat.y : (i == 2) ? pat.z : pat.w;
            o[i] = pi + (E1 * suf1 + E2 * pre2) * inv;
        }
        *(float4*)&out[(size_t)gr * D_TOT + c0] = make_float4(o[0], o[1], o[2], o[3]);
    }
}

// ============ tiny fallback (round-1, known-passing) ============
__global__ __launch_bounds__(256) void pq_fb(const float* __restrict__ patient,
                                             const float* __restrict__ disease,
                                             const float* __restrict__ ak,
                                             float* __restrict__ p,
                                             float* __restrict__ q) {
    int gid  = blockIdx.x * blockDim.x + threadIdx.x;
    int wid  = gid >> 6;
    int lane = gid & 63;
    const float* src;
    const float* a;
    float* dst;
    if (wid < B_TOT) {
        src = patient + (size_t)wid * D_TOT; a = ak; dst = p + wid;
    } else {
        src = disease + (size_t)(wid - B_TOT) * D_TOT; a = ak + D_TOT; dst = q + (wid - B_TOT);
    }
    float s = src[lane] * a[lane] + src[lane + 64] * a[lane + 64];
    #pragma unroll
    for (int off = 32; off; off >>= 1) s += __shfl_xor(s, off);
    if (lane == 0) *dst = s;
}

#define FBP 16
#define FNT 256
__global__ __launch_bounds__(256) void gat_fb(const float* __restrict__ patient,
                                              const float* __restrict__ disease,
                                              const float* __restrict__ p,
                                              const float* __restrict__ q,
                                              float* __restrict__ out) {
    __shared__ float q_s[N_TOT];
    __shared__ float w_s[FBP][FNT];
    __shared__ float m_s[FBP], S_s[FBP], pp_s[FBP];
    const int tid = threadIdx.x;
    const int b0  = blockIdx.x * FBP;
    for (int i = tid; i < N_TOT; i += 256) q_s[i] = q[i];
    if (tid < FBP) pp_s[tid] = p[b0 + tid];
    __syncthreads();
    const int wave = tid >> 6, lane = tid & 63;
    for (int pi = wave * 4; pi < wave * 4 + 4; ++pi) {
        float pp = pp_s[pi];
        float mx = -1e30f;
        for (int n = lane; n < N_TOT; n += 64) {
            float x = pp + q_s[n]; x = x > 0.0f ? x : LEAKY * x; mx = fmaxf(mx, x);
        }
        #pragma unroll
        for (int off = 32; off; off >>= 1) mx = fmaxf(mx, __shfl_xor(mx, off));
        float sum = 0.0f;
        for (int n = lane; n < N_TOT; n += 64) {
            float x = pp + q_s[n]; x = x > 0.0f ? x : LEAKY * x; sum += __expf(x - mx);
        }
        #pragma unroll
        for (int off = 32; off; off >>= 1) sum += __shfl_xor(sum, off);
        if (lane == 0) { m_s[pi] = mx; S_s[pi] = sum; }
    }
    __syncthreads();
    const int d2 = tid & 31;
    const int pg = tid >> 5;
    const int p0 = 2 * pg, p1 = 2 * pg + 1;
    float4 acc0 = make_float4(0.f, 0.f, 0.f, 0.f);
    float4 acc1 = make_float4(0.f, 0.f, 0.f, 0.f);
    for (int n0 = 0; n0 < N_TOT; n0 += FNT) {
        __syncthreads();
        for (int i = tid; i < FBP * FNT; i += 256) {
            int pi = i >> 8;
            int nt = i & (FNT - 1);
            float x = pp_s[pi] + q_s[n0 + nt];
            x = x > 0.0f ? x : LEAKY * x;
            w_s[pi][nt] = __expf(x - m_s[pi]);
        }
        __syncthreads();
        const float* drow = disease + (size_t)n0 * D_TOT + d2 * 4;
        #pragma unroll 4
        for (int nt = 0; nt < FNT; ++nt) {
            float4 dv = *reinterpret_cast<const float4*>(drow + (size_t)nt * D_TOT);
            float w0 = w_s[p0][nt];
            float w1 = w_s[p1][nt];
            acc0.x += w0 * dv.x; acc0.y += w0 * dv.y; acc0.z += w0 * dv.z; acc0.w += w0 * dv.w;
            acc1.x += w1 * dv.x; acc1.y += w1 * dv.y; acc1.z += w1 * dv.z; acc1.w += w1 * dv.w;
        }
    }
    const float inv0 = 1.0f / S_s[p0];
    const float inv1 = 1.0f / S_s[p1];
    {
        size_t off = (size_t)(b0 + p0) * D_TOT + d2 * 4;
        float4 pf = *reinterpret_cast<const float4*>(patient + off);
        float4 o;
        o.x = pf.x + acc0.x * inv0; o.y = pf.y + acc0.y * inv0;
        o.z = pf.z + acc0.z * inv0; o.w = pf.w + acc0.w * inv0;
        *reinterpret_cast<float4*>(reinterpret_cast<float*>(out) + off) = o;
    }
    {
        size_t off = (size_t)(b0 + p1) * D_TOT + d2 * 4;
        float4 pf = *reinterpret_cast<const float4*>(patient + off);
        float4 o;
        o.x = pf.x + acc1.x * inv1; o.y = pf.y + acc1.y * inv1;
        o.z = pf.z + acc1.z * inv1; o.w = pf.w + acc1.w * inv1;
        *reinterpret_cast<float4*>(reinterpret_cast<float*>(out) + off) = o;
    }
}

extern "C" void kernel_launch(void* const* d_in, const int* in_sizes, int n_in,
                              void* d_out, int out_size, void* d_ws, size_t ws_size,
                              hipStream_t stream) {
    const float* patient = (const float*)d_in[0];   // 8192 x 128
    const float* disease = (const float*)d_in[1];   // 2048 x 128
    const float* ak      = (const float*)d_in[2];   // 256
    float* out = (float*)d_out;
    char* w = (char*)d_ws;

    const size_t need_fast = 32768;   // sortedq 8KB + perm 8KB (rounded up)

    if (ws_size >= need_fast) {
        float* sq = (float*)w;                     // 2048 f32
        int*   pm = (int*)(w + 8192);              // 2048 i32
        qrank_kernel<<<N_TOT / 32, 512, 0, stream>>>(disease, ak, sq, pm);
        gat_stream<<<B_TOT / 32, 1024, 0, stream>>>(patient, disease, ak, sq, pm, out);
    } else {
        float* p = (float*)d_ws;
        float* q = p + B_TOT;
        pq_fb<<<(B_TOT + N_TOT) / 4, 256, 0, stream>>>(patient, disease, ak, p, q);
        gat_fb<<<B_TOT / FBP, 256, 0, stream>>>(patient, disease, p, q, out);
    }
}

// Round 14
// 60.154 us; speedup vs baseline: 1.7141x; 1.3008x over previous
//
#include <hip/hip_runtime.h>
#include <hip/hip_bf16.h>

#define LEAKY 0.2f
#define B_TOT 8192
#define N_TOT 2048
#define D_TOT 128
#define BM 16

typedef float f32x4 __attribute__((ext_vector_type(4)));
typedef short bf16x8 __attribute__((ext_vector_type(8)));
typedef unsigned short u16x8 __attribute__((ext_vector_type(8)));

static __device__ __forceinline__ unsigned short f2bf(float x) {
    return __builtin_bit_cast(unsigned short, __float2bfloat16(x));
}

// ============ Launch A: q-dots + rank + write sortedq AND Dsorted ============
// 64 blocks x 512 threads (R13-A proven, + permuted row copy).
__global__ __launch_bounds__(512) void qrank_kernel(const float* __restrict__ disease,
                                                    const float* __restrict__ ak,
                                                    float* __restrict__ sortedq,
                                                    float* __restrict__ Dsorted) {
    __shared__ float q_s[N_TOT];
    __shared__ float a_s[D_TOT];
    __shared__ int   rank_l[32];
    const int tid = threadIdx.x;
    if (tid < D_TOT) a_s[tid] = ak[D_TOT + tid];
    __syncthreads();

    // q-dots: half-wave per row, 4 rows in flight
    const int hw = tid >> 5, hl = tid & 31;
    const float4 av = *(const float4*)(a_s + hl * 4);
    for (int r = hw; r < N_TOT; r += 64) {
        float s[4];
        #pragma unroll
        for (int u = 0; u < 4; ++u) {
            const float4 v = *(const float4*)(disease + (size_t)(r + u * 16) * D_TOT + hl * 4);
            s[u] = v.x * av.x + v.y * av.y + v.z * av.z + v.w * av.w;
        }
        #pragma unroll
        for (int u = 0; u < 4; ++u) {
            s[u] += __shfl_xor(s[u], 16); s[u] += __shfl_xor(s[u], 8);
            s[u] += __shfl_xor(s[u], 4);  s[u] += __shfl_xor(s[u], 2);
            s[u] += __shfl_xor(s[u], 1);
        }
        if (hl == 0) {
            #pragma unroll
            for (int u = 0; u < 4; ++u) q_s[r + u * 16] = s[u];
        }
    }
    __syncthreads();

    // rank: 32 elements/block, 16 threads per element
    const int kl = tid >> 4, sub = tid & 15;
    const int k = blockIdx.x * 32 + kl;
    const float qk = q_s[k];
    int cnt = 0;
    const int j0 = sub * 128;
    #pragma unroll 8
    for (int j = j0; j < j0 + 128; ++j) {
        const float qj = q_s[j];
        cnt += (qj < qk || (qj == qk && j < k)) ? 1 : 0;
    }
    cnt += __shfl_xor(cnt, 1); cnt += __shfl_xor(cnt, 2);
    cnt += __shfl_xor(cnt, 4); cnt += __shfl_xor(cnt, 8);
    if (sub == 0) { sortedq[cnt] = qk; rank_l[kl] = cnt; }
    __syncthreads();

    // permuted copy: 32 rows x 16 threads, 8 floats (2x float4) each
    const int rl = tid >> 4, tc = tid & 15;
    const int dst = rank_l[rl];
    const float* srcp = disease + (size_t)(blockIdx.x * 32 + rl) * D_TOT + tc * 8;
    float* dstp = Dsorted + (size_t)dst * D_TOT + tc * 8;
    const float4 v0 = *(const float4*)(srcp);
    const float4 v1 = *(const float4*)(srcp + 4);
    *(float4*)(dstp)     = v0;
    *(float4*)(dstp + 4) = v1;
}

// ============ Launch B: contiguous snapshot-stream ============
// 256 blocks x 1024 threads, 32 patients/block. 32 segments x 64 rows;
// thread = (seg, col-quad), float4 loads from CONTIGUOUS Dsorted.
__global__ __launch_bounds__(1024) void gat_stream(const float* __restrict__ patient,
                                                   const float* __restrict__ Dsorted,
                                                   const float* __restrict__ ak,
                                                   const float* __restrict__ sortedq,
                                                   float* __restrict__ out) {
    __shared__ float sq[N_TOT];
    __shared__ float e1l[N_TOT], e2l[N_TOT];
    __shared__ unsigned mask[N_TOT];
    __shared__ __align__(16) float snap1[32][128], snap2[32][128];
    __shared__ __align__(16) float sseg1[33][128], sseg2[33][128];
    __shared__ float a_s[D_TOT];
    __shared__ float p_s[32], E1_s[32], E2_s[32], inv_s[32];
    __shared__ int   c_s[32];

    const int tid  = threadIdx.x;
    const int wave = tid >> 6;
    const int lane = tid & 63;
    const int b0   = blockIdx.x * 32;

    // P1: load sorted q, derive e1/e2, zero mask
    for (int i = tid; i < N_TOT; i += 1024) {
        const float s = sortedq[i];
        sq[i]  = s;
        e1l[i] = __expf(s);
        e2l[i] = __expf(LEAKY * s);
        mask[i] = 0u;
    }
    if (tid < D_TOT) a_s[tid] = ak[tid];
    __syncthreads();

    // P2: p-dots (16 waves x 2 rows)
    #pragma unroll
    for (int rr = 0; rr < 2; ++rr) {
        const int row = wave * 2 + rr;
        const float* pr = patient + (size_t)(b0 + row) * D_TOT;
        float s = pr[lane] * a_s[lane] + pr[lane + 64] * a_s[lane + 64];
        #pragma unroll
        for (int off = 32; off; off >>= 1) s += __shfl_xor(s, off);
        if (lane == 0) p_s[row] = s;
    }
    __syncthreads();

    // P3: E1/E2/S (exact max-trick) + binary search + event mask
    #pragma unroll
    for (int rr = 0; rr < 2; ++rr) {
        const int row = wave * 2 + rr;
        const float pv = p_s[row];
        const float qmax = sq[N_TOT - 1];
        const float xm = pv + qmax;
        const float m = fmaxf(xm, LEAKY * xm);       // row max (leaky monotonic)
        const float E1 = __expf(pv - m);
        const float E2 = __expf(LEAKY * pv - m);
        float s = 0.f;
        for (int n = lane; n < N_TOT; n += 64)
            s += fmaxf(E1 * e1l[n], E2 * e2l[n]);
        #pragma unroll
        for (int off = 32; off; off >>= 1) s += __shfl_xor(s, off);
        if (lane == 0) { E1_s[row] = E1; E2_s[row] = E2; inv_s[row] = 1.0f / s; }
    }
    if (tid < 32) {
        const float thr = -p_s[tid];
        int lo = 0, hi = N_TOT;
        while (lo < hi) {                            // first idx with sq[idx] > thr
            const int mid = (lo + hi) >> 1;
            if (sq[mid] <= thr) lo = mid + 1; else hi = mid;
        }
        c_s[tid] = lo;
        if (lo < N_TOT) atomicOr(&mask[lo], 1u << tid);
    }
    __syncthreads();

    // P4: contiguous descending stream. 32 segs x 64 rows; 32 col-quads.
    {
        const int seg = tid >> 5;
        const int c0  = (tid & 31) * 4;
        const int jbase = seg * 64;
        float4 r1 = make_float4(0.f, 0.f, 0.f, 0.f);
        float4 r2 = make_float4(0.f, 0.f, 0.f, 0.f);
        #pragma unroll 4
        for (int jj = 63; jj >= 0; --jj) {
            const int j = jbase + jj;
            const float4 d = *(const float4*)(Dsorted + (size_t)j * D_TOT + c0);
            const float e1 = e1l[j], e2 = e2l[j];
            r1.x = fmaf(e1, d.x, r1.x); r1.y = fmaf(e1, d.y, r1.y);
            r1.z = fmaf(e1, d.z, r1.z); r1.w = fmaf(e1, d.w, r1.w);
            r2.x = fmaf(e2, d.x, r2.x); r2.y = fmaf(e2, d.y, r2.y);
            r2.z = fmaf(e2, d.z, r2.z); r2.w = fmaf(e2, d.w, r2.w);
            unsigned mk = mask[j];
            while (mk) {
                const int r = __ffs(mk) - 1;
                mk &= mk - 1;
                *(float4*)&snap1[r][c0] = r1;
                *(float4*)&snap2[r][c0] = r2;
            }
        }
        *(float4*)&sseg1[seg][c0] = r1;
        *(float4*)&sseg2[seg][c0] = r2;
    }
    __syncthreads();

    // P5: suffix over 32 segment totals (sentinel row 32 = 0)
    if (tid < 128) {
        float a1 = 0.f, a2 = 0.f;
        sseg1[32][tid] = 0.f; sseg2[32][tid] = 0.f;
        #pragma unroll
        for (int s = 31; s >= 0; --s) {
            a1 += sseg1[s][tid]; sseg1[s][tid] = a1;
            a2 += sseg2[s][tid]; sseg2[s][tid] = a2;
        }
    }
    __syncthreads();

    // P6: output. row = tid>>5, 32 threads x 4 cols.
    {
        const int row = tid >> 5;
        const int c0 = (tid & 31) * 4;
        const int gr = b0 + row;
        const int c = c_s[row];
        const bool has = (c < N_TOT);
        const int sg1 = has ? ((c >> 6) + 1) : 32;   // segments strictly above cut
        const float E1 = E1_s[row], E2 = E2_s[row], inv = inv_s[row];
        const float4 pat = *(const float4*)&patient[(size_t)gr * D_TOT + c0];
        float o[4];
        #pragma unroll
        for (int i = 0; i < 4; ++i) {
            const int col = c0 + i;
            const float suf1 = (has ? snap1[row][col] : 0.f) + sseg1[sg1][col];
            const float suf2 = (has ? snap2[row][col] : 0.f) + sseg2[sg1][col];
            const float pre2 = sseg2[0][col] - suf2;
            const float pi = (i == 0) ? pat.x : (i == 1) ? pat.y : (i == 2) ? pat.z : pat.w;
            o[i] = pi + (E1 * suf1 + E2 * pre2) * inv;
        }
        *(float4*)&out[(size_t)gr * D_TOT + c0] = make_float4(o[0], o[1], o[2], o[3]);
    }
}

// ============ MID fallback: R11 MFMA path (26.5 µs proven) ============
__global__ __launch_bounds__(256) void prep_kernel(const float* __restrict__ disease,
                                                   const float* __restrict__ ak,
                                                   float* __restrict__ q,
                                                   uint4* __restrict__ DnTf) {
    __shared__ float tile[32][129];
    __shared__ float a_s[D_TOT];
    const int tid = threadIdx.x;
    const int b = blockIdx.x;
    const int r0 = b * 32;
    if (tid < D_TOT) a_s[tid] = ak[D_TOT + tid];
    #pragma unroll
    for (int t = 0; t < 4; ++t) {
        int idx = tid + t * 256;
        int row = idx >> 5;
        int cv = (idx & 31) * 4;
        float4 v = *(const float4*)(disease + (size_t)(r0 + row) * D_TOT + cv);
        tile[row][cv] = v.x; tile[row][cv + 1] = v.y;
        tile[row][cv + 2] = v.z; tile[row][cv + 3] = v.w;
    }
    __syncthreads();
    const int wave = tid >> 6, lane = tid & 63;
    #pragma unroll
    for (int rr = 0; rr < 8; ++rr) {
        int r = wave * 8 + rr;
        float s = tile[r][lane] * a_s[lane] + tile[r][lane + 64] * a_s[lane + 64];
        #pragma unroll
        for (int off = 32; off; off >>= 1) s += __shfl_xor(s, off);
        if (lane == 0) q[r0 + r] = s;
    }
    #pragma unroll
    for (int h = 0; h < 2; ++h) {
        const int c  = tid + h * 256;
        const int kg = c >> 7;
        const int col = c & 127;
        const int ct = col >> 4, cl = col & 15;
        unsigned u[4];
        #pragma unroll
        for (int jj = 0; jj < 4; ++jj) {
            unsigned lo = f2bf(tile[kg * 8 + 2 * jj][col]);
            unsigned hi = f2bf(tile[kg * 8 + 2 * jj + 1][col]);
            u[jj] = lo | (hi << 16);
        }
        DnTf[((size_t)b * 8 + ct) * 64 + kg * 16 + cl] = make_uint4(u[0], u[1], u[2], u[3]);
    }
}

__global__ __launch_bounds__(1024, 8) void gat_mfma(const float* __restrict__ patient,
                                                    const float* __restrict__ ak,
                                                    const float* __restrict__ q,
                                                    const uint4* __restrict__ DnTf,
                                                    float* __restrict__ out) {
    __shared__ __align__(16) float eq1_s[N_TOT];
    __shared__ __align__(16) float eq2_s[N_TOT];
    __shared__ float red_s[7][2][1024];
    __shared__ float a_s[D_TOT];
    __shared__ float p_s[BM], E1_s[BM], E2_s[BM], S_s[BM];
    __shared__ float red16[16];
    const int tid  = threadIdx.x;
    const int wave = tid >> 6;
    const int lane = tid & 63;
    const int b0   = blockIdx.x * BM;
    if (tid < D_TOT) a_s[tid] = ak[tid];
    __syncthreads();
    float mx = -1e30f;
    for (int i = tid; i < N_TOT; i += 1024) {
        float qq = q[i];
        eq1_s[i] = __expf(qq);
        eq2_s[i] = __expf(LEAKY * qq);
        mx = fmaxf(mx, qq);
    }
    #pragma unroll
    for (int off = 32; off; off >>= 1) mx = fmaxf(mx, __shfl_xor(mx, off));
    if (lane == 0) red16[wave] = mx;
    {
        const float* pr = patient + (size_t)(b0 + wave) * D_TOT;
        float s = pr[lane] * a_s[lane] + pr[lane + 64] * a_s[lane + 64];
        #pragma unroll
        for (int off = 32; off; off >>= 1) s += __shfl_xor(s, off);
        if (lane == 0) p_s[wave] = s;
    }
    __syncthreads();
    if (tid < BM) {
        float qmax = red16[0];
        #pragma unroll
        for (int i = 1; i < 16; ++i) qmax = fmaxf(qmax, red16[i]);
        const float pv = p_s[tid];
        const float xm = pv + qmax;
        const float m = fmaxf(xm, LEAKY * xm);
        E1_s[tid] = __expf(pv - m);
        E2_s[tid] = __expf(LEAKY * pv - m);
    }
    __syncthreads();
    {
        const float E1 = E1_s[wave], E2 = E2_s[wave];
        float s = 0.f;
        for (int n = lane; n < N_TOT; n += 64)
            s += fmaxf(E1 * eq1_s[n], E2 * eq2_s[n]);
        #pragma unroll
        for (int off = 32; off; off >>= 1) s += __shfl_xor(s, off);
        if (lane == 0) S_s[wave] = s;
    }
    __syncthreads();
    const int cl = lane & 15;
    const int kg = lane >> 4;
    const int cw = wave & 1;
    const int kq = wave >> 1;
    const float E1A = E1_s[cl], E2A = E2_s[cl];
    const uint4* fbase = DnTf + (size_t)(cw * 4) * 64 + lane;
    f32x4 acc[4] = {};
    for (int kt = kq * 8; kt < kq * 8 + 8; ++kt) {
        const uint4* fp = fbase + (size_t)kt * 512;
        const uint4 b0v = fp[0];
        const uint4 b1v = fp[64];
        const uint4 b2v = fp[128];
        const uint4 b3v = fp[192];
        const int gk = kt * 32 + kg * 8;
        u16x8 aw;
        {
            const float4 e1 = *(const float4*)&eq1_s[gk];
            const float4 e2 = *(const float4*)&eq2_s[gk];
            aw[0] = f2bf(fmaxf(E1A * e1.x, E2A * e2.x));
            aw[1] = f2bf(fmaxf(E1A * e1.y, E2A * e2.y));
            aw[2] = f2bf(fmaxf(E1A * e1.z, E2A * e2.z));
            aw[3] = f2bf(fmaxf(E1A * e1.w, E2A * e2.w));
        }
        {
            const float4 e1 = *(const float4*)&eq1_s[gk + 4];
            const float4 e2 = *(const float4*)&eq2_s[gk + 4];
            aw[4] = f2bf(fmaxf(E1A * e1.x, E2A * e2.x));
            aw[5] = f2bf(fmaxf(E1A * e1.y, E2A * e2.y));
            aw[6] = f2bf(fmaxf(E1A * e1.z, E2A * e2.z));
            aw[7] = f2bf(fmaxf(E1A * e1.w, E2A * e2.w));
        }
        const bf16x8 a0 = __builtin_bit_cast(bf16x8, aw);
        acc[0] = __builtin_amdgcn_mfma_f32_16x16x32_bf16(a0, __builtin_bit_cast(bf16x8, b0v), acc[0], 0, 0, 0);
        acc[1] = __builtin_amdgcn_mfma_f32_16x16x32_bf16(a0, __builtin_bit_cast(bf16x8, b1v), acc[1], 0, 0, 0);
        acc[2] = __builtin_amdgcn_mfma_f32_16x16x32_bf16(a0, __builtin_bit_cast(bf16x8, b2v), acc[2], 0, 0, 0);
        acc[3] = __builtin_amdgcn_mfma_f32_16x16x32_bf16(a0, __builtin_bit_cast(bf16x8, b3v), acc[3], 0, 0, 0);
    }
    __syncthreads();
    if (kq > 0) {
        float* rb = &red_s[kq - 1][cw][0];
        #pragma unroll
        for (int t = 0; t < 4; ++t)
            #pragma unroll
            for (int i = 0; i < 4; ++i)
                rb[t * 256 + (kg * 4 + i) * 16 + cl] = acc[t][i];
    }
    __syncthreads();
    if (kq == 0) {
        #pragma unroll
        for (int t = 0; t < 4; ++t)
            #pragma unroll
            for (int i = 0; i < 4; ++i) {
                const int idx = t * 256 + (kg * 4 + i) * 16 + cl;
                float s = acc[t][i];
                #pragma unroll
                for (int j = 0; j < 7; ++j) s += red_s[j][cw][idx];
                acc[t][i] = s;
            }
        float inv[4];
        #pragma unroll
        for (int i = 0; i < 4; ++i) inv[i] = 1.0f / S_s[kg * 4 + i];
        #pragma unroll
        for (int t = 0; t < 4; ++t)
            #pragma unroll
            for (int i = 0; i < 4; ++i) {
                const int row = b0 + kg * 4 + i;
                const int col = cw * 64 + t * 16 + cl;
                out[(size_t)row * D_TOT + col] =
                    patient[(size_t)row * D_TOT + col] + acc[t][i] * inv[i];
            }
    }
}

// ============ tiny fallback (round-1) ============
__global__ __launch_bounds__(256) void pq_fb(const float* __restrict__ patient,
                                             const float* __restrict__ disease,
                                             const float* __restrict__ ak,
                                             float* __restrict__ p,
                                             float* __restrict__ q) {
    int gid  = blockIdx.x * blockDim.x + threadIdx.x;
    int wid  = gid >> 6;
    int lane = gid & 63;
    const float* src;
    const float* a;
    float* dst;
    if (wid < B_TOT) {
        src = patient + (size_t)wid * D_TOT; a = ak; dst = p + wid;
    } else {
        src = disease + (size_t)(wid - B_TOT) * D_TOT; a = ak + D_TOT; dst = q + (wid - B_TOT);
    }
    float s = src[lane] * a[lane] + src[lane + 64] * a[lane + 64];
    #pragma unroll
    for (int off = 32; off; off >>= 1) s += __shfl_xor(s, off);
    if (lane == 0) *dst = s;
}

#define FBP 16
#define FNT 256
__global__ __launch_bounds__(256) void gat_fb(const float* __restrict__ patient,
                                              const float* __restrict__ disease,
                                              const float* __restrict__ p,
                                              const float* __restrict__ q,
                                              float* __restrict__ out) {
    __shared__ float q_s[N_TOT];
    __shared__ float w_s[FBP][FNT];
    __shared__ float m_s[FBP], S_s[FBP], pp_s[FBP];
    const int tid = threadIdx.x;
    const int b0  = blockIdx.x * FBP;
    for (int i = tid; i < N_TOT; i += 256) q_s[i] = q[i];
    if (tid < FBP) pp_s[tid] = p[b0 + tid];
    __syncthreads();
    const int wave = tid >> 6, lane = tid & 63;
    for (int pi = wave * 4; pi < wave * 4 + 4; ++pi) {
        float pp = pp_s[pi];
        float mx = -1e30f;
        for (int n = lane; n < N_TOT; n += 64) {
            float x = pp + q_s[n]; x = x > 0.0f ? x : LEAKY * x; mx = fmaxf(mx, x);
        }
        #pragma unroll
        for (int off = 32; off; off >>= 1) mx = fmaxf(mx, __shfl_xor(mx, off));
        float sum = 0.0f;
        for (int n = lane; n < N_TOT; n += 64) {
            float x = pp + q_s[n]; x = x > 0.0f ? x : LEAKY * x; sum += __expf(x - mx);
        }
        #pragma unroll
        for (int off = 32; off; off >>= 1) sum += __shfl_xor(sum, off);
        if (lane == 0) { m_s[pi] = mx; S_s[pi] = sum; }
    }
    __syncthreads();
    const int d2 = tid & 31;
    const int pg = tid >> 5;
    const int p0 = 2 * pg, p1 = 2 * pg + 1;
    float4 acc0 = make_float4(0.f, 0.f, 0.f, 0.f);
    float4 acc1 = make_float4(0.f, 0.f, 0.f, 0.f);
    for (int n0 = 0; n0 < N_TOT; n0 += FNT) {
        __syncthreads();
        for (int i = tid; i < FBP * FNT; i += 256) {
            int pi = i >> 8;
            int nt = i & (FNT - 1);
            float x = pp_s[pi] + q_s[n0 + nt];
            x = x > 0.0f ? x : LEAKY * x;
            w_s[pi][nt] = __expf(x - m_s[pi]);
        }
        __syncthreads();
        const float* drow = disease + (size_t)n0 * D_TOT + d2 * 4;
        #pragma unroll 4
        for (int nt = 0; nt < FNT; ++nt) {
            float4 dv = *reinterpret_cast<const float4*>(drow + (size_t)nt * D_TOT);
            float w0 = w_s[p0][nt];
            float w1 = w_s[p1][nt];
            acc0.x += w0 * dv.x; acc0.y += w0 * dv.y; acc0.z += w0 * dv.z; acc0.w += w0 * dv.w;
            acc1.x += w1 * dv.x; acc1.y += w1 * dv.y; acc1.z += w1 * dv.z; acc1.w += w1 * dv.w;
        }
    }
    const float inv0 = 1.0f / S_s[p0];
    const float inv1 = 1.0f / S_s[p1];
    {
        size_t off = (size_t)(b0 + p0) * D_TOT + d2 * 4;
        float4 pf = *reinterpret_cast<const float4*>(patient + off);
        float4 o;
        o.x = pf.x + acc0.x * inv0; o.y = pf.y + acc0.y * inv0;
        o.z = pf.z + acc0.z * inv0; o.w = pf.w + acc0.w * inv0;
        *reinterpret_cast<float4*>(reinterpret_cast<float*>(out) + off) = o;
    }
    {
        size_t off = (size_t)(b0 + p1) * D_TOT + d2 * 4;
        float4 pf = *reinterpret_cast<const float4*>(patient + off);
        float4 o;
        o.x = pf.x + acc1.x * inv1; o.y = pf.y + acc1.y * inv1;
        o.z = pf.z + acc1.z * inv1; o.w = pf.w + acc1.w * inv1;
        *reinterpret_cast<float4*>(reinterpret_cast<float*>(out) + off) = o;
    }
}

extern "C" void kernel_launch(void* const* d_in, const int* in_sizes, int n_in,
                              void* d_out, int out_size, void* d_ws, size_t ws_size,
                              hipStream_t stream) {
    const float* patient = (const float*)d_in[0];   // 8192 x 128
    const float* disease = (const float*)d_in[1];   // 2048 x 128
    const float* ak      = (const float*)d_in[2];   // 256
    float* out = (float*)d_out;
    char* w = (char*)d_ws;

    const size_t need_fast = 8192 + (size_t)N_TOT * D_TOT * 4;   // sortedq + Dsorted = 1.06 MB
    const size_t need_mid  = (size_t)512 * 1024 + 8192;

    if (ws_size >= need_fast) {
        float* sq = (float*)w;                       // 2048 f32
        float* Ds = (float*)(w + 8192);              // 2048 x 128 f32
        qrank_kernel<<<N_TOT / 32, 512, 0, stream>>>(disease, ak, sq, Ds);
        gat_stream<<<B_TOT / 32, 1024, 0, stream>>>(patient, Ds, ak, sq, out);
    } else if (ws_size >= need_mid) {
        uint4* DnTf = (uint4*)d_ws;
        float* q    = (float*)(w + 512 * 1024);
        prep_kernel<<<N_TOT / 32, 256, 0, stream>>>(disease, ak, q, DnTf);
        gat_mfma<<<B_TOT / BM, 1024, 0, stream>>>(patient, ak, q, DnTf, out);
    } else {
        float* p = (float*)d_ws;
        float* q = p + B_TOT;
        pq_fb<<<(B_TOT + N_TOT) / 4, 256, 0, stream>>>(patient, disease, ak, p, q);
        gat_fb<<<B_TOT / FBP, 256, 0, stream>>>(patient, disease, p, q, out);
    }
}

// Round 15
// 26.818 us; speedup vs baseline: 3.8449x; 2.2431x over previous
//
#include <hip/hip_runtime.h>
#include <hip/hip_bf16.h>

#define LEAKY 0.2f
#define B_TOT 8192
#define N_TOT 2048
#define D_TOT 128
#define BM 16

typedef float f32x4 __attribute__((ext_vector_type(4)));
typedef short bf16x8 __attribute__((ext_vector_type(8)));
typedef unsigned short u16x8 __attribute__((ext_vector_type(8)));

static __device__ __forceinline__ unsigned short f2bf(float x) {
    return __builtin_bit_cast(unsigned short, __float2bfloat16(x));
}

// ---------------- prep: q-dots + fragment-ordered bf16 DnT ----------------
__global__ __launch_bounds__(256) void prep_kernel(const float* __restrict__ disease,
                                                   const float* __restrict__ ak,
                                                   float* __restrict__ q,
                                                   uint4* __restrict__ DnTf) {
    __shared__ float tile[32][129];   // +1 pad
    __shared__ float a_s[D_TOT];
    const int tid = threadIdx.x;
    const int b = blockIdx.x;
    const int r0 = b * 32;

    if (tid < D_TOT) a_s[tid] = ak[D_TOT + tid];
    #pragma unroll
    for (int t = 0; t < 4; ++t) {
        int idx = tid + t * 256;          // 0..1023 float4 slots
        int row = idx >> 5;
        int cv = (idx & 31) * 4;
        float4 v = *(const float4*)(disease + (size_t)(r0 + row) * D_TOT + cv);
        tile[row][cv] = v.x; tile[row][cv + 1] = v.y;
        tile[row][cv + 2] = v.z; tile[row][cv + 3] = v.w;
    }
    __syncthreads();

    const int wave = tid >> 6, lane = tid & 63;
    #pragma unroll
    for (int rr = 0; rr < 8; ++rr) {
        int r = wave * 8 + rr;
        float s = tile[r][lane] * a_s[lane] + tile[r][lane + 64] * a_s[lane + 64];
        #pragma unroll
        for (int off = 32; off; off >>= 1) s += __shfl_xor(s, off);
        if (lane == 0) q[r0 + r] = s;
    }

    #pragma unroll
    for (int h = 0; h < 2; ++h) {
        const int c  = tid + h * 256;     // 0..511
        const int kg = c >> 7;            // 0..3
        const int col = c & 127;
        const int ct = col >> 4, cl = col & 15;
        unsigned u[4];
        #pragma unroll
        for (int jj = 0; jj < 4; ++jj) {
            unsigned lo = f2bf(tile[kg * 8 + 2 * jj][col]);
            unsigned hi = f2bf(tile[kg * 8 + 2 * jj + 1][col]);
            u[jj] = lo | (hi << 16);
        }
        DnTf[((size_t)b * 8 + ct) * 64 + kg * 16 + cl] = make_uint4(u[0], u[1], u[2], u[3]);
    }
}

// ---------------- main: register-lean, true 8 waves/SIMD ----------------
// 512 blocks x 1024 threads, 2 blocks/CU. 16 waves = cw(2) x kq(8).
__global__ __launch_bounds__(1024, 8) void gat_mfma(const float* __restrict__ patient,
                                                    const float* __restrict__ ak,
                                                    const float* __restrict__ q,
                                                    const uint4* __restrict__ DnTf,
                                                    float* __restrict__ out) {
    __shared__ __align__(16) float eq1_s[N_TOT];
    __shared__ __align__(16) float eq2_s[N_TOT];
    __shared__ float red_s[7][2][1024];   // [kq-1][cw][t*256+(kg*4+i)*16+cl]
    __shared__ float a_s[D_TOT];
    __shared__ float p_s[BM], E1_s[BM], E2_s[BM], S_s[BM];
    __shared__ float red16[16];

    const int tid  = threadIdx.x;
    const int wave = tid >> 6;
    const int lane = tid & 63;
    const int b0   = blockIdx.x * BM;

    if (tid < D_TOT) a_s[tid] = ak[tid];
    __syncthreads();

    // eq1/eq2 + qmax partials
    float mx = -1e30f;
    for (int i = tid; i < N_TOT; i += 1024) {
        float qq = q[i];
        eq1_s[i] = __expf(qq);
        eq2_s[i] = __expf(LEAKY * qq);
        mx = fmaxf(mx, qq);
    }
    #pragma unroll
    for (int off = 32; off; off >>= 1) mx = fmaxf(mx, __shfl_xor(mx, off));
    if (lane == 0) red16[wave] = mx;

    // p-dot: wave w handles row w
    {
        const float* pr = patient + (size_t)(b0 + wave) * D_TOT;
        float s = pr[lane] * a_s[lane] + pr[lane + 64] * a_s[lane + 64];
        #pragma unroll
        for (int off = 32; off; off >>= 1) s += __shfl_xor(s, off);
        if (lane == 0) p_s[wave] = s;
    }
    __syncthreads();

    if (tid < BM) {
        float qmax = red16[0];
        #pragma unroll
        for (int i = 1; i < 16; ++i) qmax = fmaxf(qmax, red16[i]);
        const float pv = p_s[tid];
        const float xm = pv + qmax;
        const float m = fmaxf(xm, LEAKY * xm);    // row max (leaky monotonic)
        E1_s[tid] = __expf(pv - m);
        E2_s[tid] = __expf(LEAKY * pv - m);
    }
    __syncthreads();

    // S per row (wave w -> row w): S = sum_n max(E1*eq1, E2*eq2)  (exact)
    {
        const float E1 = E1_s[wave], E2 = E2_s[wave];
        float s = 0.f;
        for (int n = lane; n < N_TOT; n += 64)
            s += fmaxf(E1 * eq1_s[n], E2 * eq2_s[n]);
        #pragma unroll
        for (int off = 32; off; off >>= 1) s += __shfl_xor(s, off);
        if (lane == 0) S_s[wave] = s;
    }
    __syncthreads();

    // ---- barrier-free MFMA K-loop (register-lean) ----
    const int cl = lane & 15;
    const int kg = lane >> 4;
    const int cw = wave & 1;          // 64-col half
    const int kq = wave >> 1;         // K eighth (0..7)

    const float E1A = E1_s[cl], E2A = E2_s[cl];
    const uint4* fbase = DnTf + (size_t)(cw * 4) * 64 + lane;   // + kt*512 + t*64

    f32x4 acc[4] = {};

    for (int kt = kq * 8; kt < kq * 8 + 8; ++kt) {
        const uint4* fp = fbase + (size_t)kt * 512;
        const uint4 b0v = fp[0];
        const uint4 b1v = fp[64];
        const uint4 b2v = fp[128];
        const uint4 b3v = fp[192];

        const int gk = kt * 32 + kg * 8;
        u16x8 aw;
        {
            const float4 e1 = *(const float4*)&eq1_s[gk];
            const float4 e2 = *(const float4*)&eq2_s[gk];
            aw[0] = f2bf(fmaxf(E1A * e1.x, E2A * e2.x));
            aw[1] = f2bf(fmaxf(E1A * e1.y, E2A * e2.y));
            aw[2] = f2bf(fmaxf(E1A * e1.z, E2A * e2.z));
            aw[3] = f2bf(fmaxf(E1A * e1.w, E2A * e2.w));
        }
        {
            const float4 e1 = *(const float4*)&eq1_s[gk + 4];
            const float4 e2 = *(const float4*)&eq2_s[gk + 4];
            aw[4] = f2bf(fmaxf(E1A * e1.x, E2A * e2.x));
            aw[5] = f2bf(fmaxf(E1A * e1.y, E2A * e2.y));
            aw[6] = f2bf(fmaxf(E1A * e1.z, E2A * e2.z));
            aw[7] = f2bf(fmaxf(E1A * e1.w, E2A * e2.w));
        }
        const bf16x8 a0 = __builtin_bit_cast(bf16x8, aw);

        acc[0] = __builtin_amdgcn_mfma_f32_16x16x32_bf16(a0, __builtin_bit_cast(bf16x8, b0v), acc[0], 0, 0, 0);
        acc[1] = __builtin_amdgcn_mfma_f32_16x16x32_bf16(a0, __builtin_bit_cast(bf16x8, b1v), acc[1], 0, 0, 0);
        acc[2] = __builtin_amdgcn_mfma_f32_16x16x32_bf16(a0, __builtin_bit_cast(bf16x8, b2v), acc[2], 0, 0, 0);
        acc[3] = __builtin_amdgcn_mfma_f32_16x16x32_bf16(a0, __builtin_bit_cast(bf16x8, b3v), acc[3], 0, 0, 0);
    }

    // ---- split-K reduction ----
    __syncthreads();
    if (kq > 0) {
        float* rb = &red_s[kq - 1][cw][0];
        #pragma unroll
        for (int t = 0; t < 4; ++t)
            #pragma unroll
            for (int i = 0; i < 4; ++i)
                rb[t * 256 + (kg * 4 + i) * 16 + cl] = acc[t][i];
    }
    __syncthreads();
    if (kq == 0) {
        #pragma unroll
        for (int t = 0; t < 4; ++t)
            #pragma unroll
            for (int i = 0; i < 4; ++i) {
                const int idx = t * 256 + (kg * 4 + i) * 16 + cl;
                float s = acc[t][i];
                #pragma unroll
                for (int j = 0; j < 7; ++j) s += red_s[j][cw][idx];
                acc[t][i] = s;
            }
        float inv[4];
        #pragma unroll
        for (int i = 0; i < 4; ++i) inv[i] = 1.0f / S_s[kg * 4 + i];
        #pragma unroll
        for (int t = 0; t < 4; ++t)
            #pragma unroll
            for (int i = 0; i < 4; ++i) {
                const int row = b0 + kg * 4 + i;
                const int col = cw * 64 + t * 16 + cl;
                out[(size_t)row * D_TOT + col] =
                    patient[(size_t)row * D_TOT + col] + acc[t][i] * inv[i];
            }
    }
}

// ---------------- fallback path (round-1, known-passing) ----------------
__global__ __launch_bounds__(256) void pq_fb(const float* __restrict__ patient,
                                             const float* __restrict__ disease,
                                             const float* __restrict__ ak,
                                             float* __restrict__ p,
                                             float* __restrict__ q) {
    int gid  = blockIdx.x * blockDim.x + threadIdx.x;
    int wid  = gid >> 6;
    int lane = gid & 63;
    const float* src;
    const float* a;
    float* dst;
    if (wid < B_TOT) {
        src = patient + (size_t)wid * D_TOT; a = ak; dst = p + wid;
    } else {
        src = disease + (size_t)(wid - B_TOT) * D_TOT; a = ak + D_TOT; dst = q + (wid - B_TOT);
    }
    float s = src[lane] * a[lane] + src[lane + 64] * a[lane + 64];
    #pragma unroll
    for (int off = 32; off; off >>= 1) s += __shfl_xor(s, off);
    if (lane == 0) *dst = s;
}

#define FBP 16
#define FNT 256
__global__ __launch_bounds__(256) void gat_fb(const float* __restrict__ patient,
                                              const float* __restrict__ disease,
                                              const float* __restrict__ p,
                                              const float* __restrict__ q,
                                              float* __restrict__ out) {
    __shared__ float q_s[N_TOT];
    __shared__ float w_s[FBP][FNT];
    __shared__ float m_s[FBP], S_s[FBP], pp_s[FBP];
    const int tid = threadIdx.x;
    const int b0  = blockIdx.x * FBP;
    for (int i = tid; i < N_TOT; i += 256) q_s[i] = q[i];
    if (tid < FBP) pp_s[tid] = p[b0 + tid];
    __syncthreads();
    const int wave = tid >> 6, lane = tid & 63;
    for (int pi = wave * 4; pi < wave * 4 + 4; ++pi) {
        float pp = pp_s[pi];
        float mx = -1e30f;
        for (int n = lane; n < N_TOT; n += 64) {
            float x = pp + q_s[n]; x = x > 0.0f ? x : LEAKY * x; mx = fmaxf(mx, x);
        }
        #pragma unroll
        for (int off = 32; off; off >>= 1) mx = fmaxf(mx, __shfl_xor(mx, off));
        float sum = 0.0f;
        for (int n = lane; n < N_TOT; n += 64) {
            float x = pp + q_s[n]; x = x > 0.0f ? x : LEAKY * x; sum += __expf(x - mx);
        }
        #pragma unroll
        for (int off = 32; off; off >>= 1) sum += __shfl_xor(sum, off);
        if (lane == 0) { m_s[pi] = mx; S_s[pi] = sum; }
    }
    __syncthreads();
    const int d2 = tid & 31;
    const int pg = tid >> 5;
    const int p0 = 2 * pg, p1 = 2 * pg + 1;
    float4 acc0 = make_float4(0.f, 0.f, 0.f, 0.f);
    float4 acc1 = make_float4(0.f, 0.f, 0.f, 0.f);
    for (int n0 = 0; n0 < N_TOT; n0 += FNT) {
        __syncthreads();
        for (int i = tid; i < FBP * FNT; i += 256) {
            int pi = i >> 8;
            int nt = i & (FNT - 1);
            float x = pp_s[pi] + q_s[n0 + nt];
            x = x > 0.0f ? x : LEAKY * x;
            w_s[pi][nt] = __expf(x - m_s[pi]);
        }
        __syncthreads();
        const float* drow = disease + (size_t)n0 * D_TOT + d2 * 4;
        #pragma unroll 4
        for (int nt = 0; nt < FNT; ++nt) {
            float4 dv = *reinterpret_cast<const float4*>(drow + (size_t)nt * D_TOT);
            float w0 = w_s[p0][nt];
            float w1 = w_s[p1][nt];
            acc0.x += w0 * dv.x; acc0.y += w0 * dv.y; acc0.z += w0 * dv.z; acc0.w += w0 * dv.w;
            acc1.x += w1 * dv.x; acc1.y += w1 * dv.y; acc1.z += w1 * dv.z; acc1.w += w1 * dv.w;
        }
    }
    const float inv0 = 1.0f / S_s[p0];
    const float inv1 = 1.0f / S_s[p1];
    {
        size_t off = (size_t)(b0 + p0) * D_TOT + d2 * 4;
        float4 pf = *reinterpret_cast<const float4*>(patient + off);
        float4 o;
        o.x = pf.x + acc0.x * inv0; o.y = pf.y + acc0.y * inv0;
        o.z = pf.z + acc0.z * inv0; o.w = pf.w + acc0.w * inv0;
        *reinterpret_cast<float4*>(reinterpret_cast<float*>(out) + off) = o;
    }
    {
        size_t off = (size_t)(b0 + p1) * D_TOT + d2 * 4;
        float4 pf = *reinterpret_cast<const float4*>(patient + off);
        float4 o;
        o.x = pf.x + acc1.x * inv1; o.y = pf.y + acc1.y * inv1;
        o.z = pf.z + acc1.z * inv1; o.w = pf.w + acc1.w * inv1;
        *reinterpret_cast<float4*>(reinterpret_cast<float*>(out) + off) = o;
    }
}

extern "C" void kernel_launch(void* const* d_in, const int* in_sizes, int n_in,
                              void* d_out, int out_size, void* d_ws, size_t ws_size,
                              hipStream_t stream) {
    const float* patient = (const float*)d_in[0];   // 8192 x 128
    const float* disease = (const float*)d_in[1];   // 2048 x 128
    const float* ak      = (const float*)d_in[2];   // 256
    float* out = (float*)d_out;

    const size_t need_fast = (size_t)512 * 1024 + 8192;   // DnTf (512KB) + q (8KB)
    if (ws_size >= need_fast) {
        uint4* DnTf = (uint4*)d_ws;                          // 64x8x64 uint4 = 512KB
        float* q    = (float*)((char*)d_ws + 512 * 1024);    // 2048 f32
        prep_kernel<<<N_TOT / 32, 256, 0, stream>>>(disease, ak, q, DnTf);
        gat_mfma<<<B_TOT / BM, 1024, 0, stream>>>(patient, ak, q, DnTf, out);
    } else {
        float* p = (float*)d_ws;          // 8192 f32
        float* q = p + B_TOT;             // 2048 f32
        pq_fb<<<(B_TOT + N_TOT) / 4, 256, 0, stream>>>(patient, disease, ak, p, q);
        gat_fb<<<B_TOT / FBP, 256, 0, stream>>>(patient, disease, p, q, out);
    }
}

// Round 16
// 25.907 us; speedup vs baseline: 3.9801x; 1.0352x over previous
//
#include <hip/hip_runtime.h>
#include <hip/hip_bf16.h>

#define LEAKY 0.2f
#define B_TOT 8192
#define N_TOT 2048
#define D_TOT 128
#define BM 32

typedef float f32x16 __attribute__((ext_vector_type(16)));
typedef short bf16x8 __attribute__((ext_vector_type(8)));
typedef unsigned short u16x8 __attribute__((ext_vector_type(8)));

static __device__ __forceinline__ unsigned short f2bf(float x) {
    return __builtin_bit_cast(unsigned short, __float2bfloat16(x));
}

// ---------------- prep: q-dots + 32x32x16-fragment-ordered bf16 DnT ----------------
// Block b: disease rows [b*32, b*32+32) = k-tiles 2b, 2b+1 (16 k each).
// Fragment (kt, ct): uint4 at (kt*4+ct)*64+lane holds B[k=kt*16+(lane>>5)*8+j][col=ct*32+(lane&31)].
__global__ __launch_bounds__(256) void prep_kernel(const float* __restrict__ disease,
                                                   const float* __restrict__ ak,
                                                   float* __restrict__ q,
                                                   uint4* __restrict__ DnTf) {
    __shared__ float tile[32][129];   // +1 pad
    __shared__ float a_s[D_TOT];
    const int tid = threadIdx.x;
    const int b = blockIdx.x;
    const int r0 = b * 32;

    if (tid < D_TOT) a_s[tid] = ak[D_TOT + tid];
    #pragma unroll
    for (int t = 0; t < 4; ++t) {
        int idx = tid + t * 256;          // 0..1023 float4 slots
        int row = idx >> 5;
        int cv = (idx & 31) * 4;
        float4 v = *(const float4*)(disease + (size_t)(r0 + row) * D_TOT + cv);
        tile[row][cv] = v.x; tile[row][cv + 1] = v.y;
        tile[row][cv + 2] = v.z; tile[row][cv + 3] = v.w;
    }
    __syncthreads();

    const int wave = tid >> 6, lane = tid & 63;
    #pragma unroll
    for (int rr = 0; rr < 8; ++rr) {
        int r = wave * 8 + rr;
        float s = tile[r][lane] * a_s[lane] + tile[r][lane + 64] * a_s[lane + 64];
        #pragma unroll
        for (int off = 32; off; off >>= 1) s += __shfl_xor(s, off);
        if (lane == 0) q[r0 + r] = s;
    }

    #pragma unroll
    for (int h = 0; h < 2; ++h) {
        const int ci = tid + h * 256;     // 0..511
        const int f  = ci >> 6;           // fragment 0..7 = lt*4+ct
        const int ln = ci & 63;
        const int lt = f >> 2, ct = f & 3;
        const int g  = ln >> 5, c = ln & 31;
        const int rb = lt * 16 + g * 8;
        unsigned u[4];
        #pragma unroll
        for (int jj = 0; jj < 4; ++jj) {
            unsigned lo = f2bf(tile[rb + 2 * jj][ct * 32 + c]);
            unsigned hi = f2bf(tile[rb + 2 * jj + 1][ct * 32 + c]);
            u[jj] = lo | (hi << 16);
        }
        DnTf[((size_t)(2 * b + lt) * 4 + ct) * 64 + ln] = make_uint4(u[0], u[1], u[2], u[3]);
    }
}

// ---------------- main: 32x32x16 MFMA, BM=32, half the L2 traffic ----------------
// 256 blocks x 1024 threads (1 block/CU). 16 waves = cw(2 col-halves) x kq(8).
__global__ __launch_bounds__(1024, 4) void gat_mfma32(const float* __restrict__ patient,
                                                      const float* __restrict__ ak,
                                                      const float* __restrict__ q,
                                                      const uint4* __restrict__ DnTf,
                                                      float* __restrict__ out) {
    __shared__ __align__(16) float eq1_s[N_TOT];
    __shared__ __align__(16) float eq2_s[N_TOT];
    __shared__ float red_s[7][2][2048];   // [kq-1][cw][row_local*64 + t*32 + c]
    __shared__ float a_s[D_TOT];
    __shared__ float p_s[BM], E1_s[BM], E2_s[BM], S_s[BM];
    __shared__ float red16[16];

    const int tid  = threadIdx.x;
    const int wave = tid >> 6;
    const int lane = tid & 63;
    const int b0   = blockIdx.x * BM;

    if (tid < D_TOT) a_s[tid] = ak[tid];
    __syncthreads();

    // eq1/eq2 + qmax partials
    float mx = -1e30f;
    for (int i = tid; i < N_TOT; i += 1024) {
        float qq = q[i];
        eq1_s[i] = __expf(qq);
        eq2_s[i] = __expf(LEAKY * qq);
        mx = fmaxf(mx, qq);
    }
    #pragma unroll
    for (int off = 32; off; off >>= 1) mx = fmaxf(mx, __shfl_xor(mx, off));
    if (lane == 0) red16[wave] = mx;

    // p-dots: wave w -> rows 2w, 2w+1
    #pragma unroll
    for (int rr = 0; rr < 2; ++rr) {
        const int row = wave * 2 + rr;
        const float* pr = patient + (size_t)(b0 + row) * D_TOT;
        float s = pr[lane] * a_s[lane] + pr[lane + 64] * a_s[lane + 64];
        #pragma unroll
        for (int off = 32; off; off >>= 1) s += __shfl_xor(s, off);
        if (lane == 0) p_s[row] = s;
    }
    __syncthreads();

    if (tid < BM) {
        float qmax = red16[0];
        #pragma unroll
        for (int i = 1; i < 16; ++i) qmax = fmaxf(qmax, red16[i]);
        const float pv = p_s[tid];
        const float xm = pv + qmax;
        const float m = fmaxf(xm, LEAKY * xm);    // row max (leaky monotonic)
        E1_s[tid] = __expf(pv - m);
        E2_s[tid] = __expf(LEAKY * pv - m);
    }
    __syncthreads();

    // S per row (wave w -> rows 2w, 2w+1): S = sum_n max(E1*eq1, E2*eq2)  (exact)
    #pragma unroll
    for (int rr = 0; rr < 2; ++rr) {
        const int row = wave * 2 + rr;
        const float E1 = E1_s[row], E2 = E2_s[row];
        float s = 0.f;
        for (int n = lane; n < N_TOT; n += 64)
            s += fmaxf(E1 * eq1_s[n], E2 * eq2_s[n]);
        #pragma unroll
        for (int off = 32; off; off >>= 1) s += __shfl_xor(s, off);
        if (lane == 0) S_s[row] = s;
    }
    __syncthreads();

    // ---- barrier-free 32x32x16 MFMA K-loop ----
    const int c31 = lane & 31;        // A row / B,D col
    const int g   = lane >> 5;        // k-group (0/1)
    const int cw  = wave & 1;         // 64-col half
    const int kq  = wave >> 1;        // K eighth (0..7), 16 k-tiles each

    const float E1A = E1_s[c31], E2A = E2_s[c31];
    const uint4* fbase = DnTf + (size_t)(cw * 2) * 64 + lane;   // + kt*256 (+64 for t=1)

    f32x16 acc0{}, acc1{};

    for (int kt = kq * 16; kt < kq * 16 + 16; ++kt) {
        const uint4* fp = fbase + (size_t)kt * 256;
        const uint4 bv0 = fp[0];
        const uint4 bv1 = fp[64];

        const int gk = kt * 16 + g * 8;
        u16x8 aw;
        {
            const float4 e1 = *(const float4*)&eq1_s[gk];
            const float4 e2 = *(const float4*)&eq2_s[gk];
            aw[0] = f2bf(fmaxf(E1A * e1.x, E2A * e2.x));
            aw[1] = f2bf(fmaxf(E1A * e1.y, E2A * e2.y));
            aw[2] = f2bf(fmaxf(E1A * e1.z, E2A * e2.z));
            aw[3] = f2bf(fmaxf(E1A * e1.w, E2A * e2.w));
        }
        {
            const float4 e1 = *(const float4*)&eq1_s[gk + 4];
            const float4 e2 = *(const float4*)&eq2_s[gk + 4];
            aw[4] = f2bf(fmaxf(E1A * e1.x, E2A * e2.x));
            aw[5] = f2bf(fmaxf(E1A * e1.y, E2A * e2.y));
            aw[6] = f2bf(fmaxf(E1A * e1.z, E2A * e2.z));
            aw[7] = f2bf(fmaxf(E1A * e1.w, E2A * e2.w));
        }
        const bf16x8 a0 = __builtin_bit_cast(bf16x8, aw);

        acc0 = __builtin_amdgcn_mfma_f32_32x32x16_bf16(a0, __builtin_bit_cast(bf16x8, bv0), acc0, 0, 0, 0);
        acc1 = __builtin_amdgcn_mfma_f32_32x32x16_bf16(a0, __builtin_bit_cast(bf16x8, bv1), acc1, 0, 0, 0);
    }

    // ---- split-K reduction ----
    // C/D map (HW-verified): col = lane&31, row_local = (reg&3) + 8*(reg>>2) + 4*(lane>>5)
    __syncthreads();
    if (kq > 0) {
        float* rb = &red_s[kq - 1][cw][0];
        #pragma unroll
        for (int rg = 0; rg < 16; ++rg) {
            const int rl = (rg & 3) + 8 * (rg >> 2) + 4 * g;
            rb[rl * 64 + c31]      = acc0[rg];
            rb[rl * 64 + 32 + c31] = acc1[rg];
        }
    }
    __syncthreads();
    if (kq == 0) {
        #pragma unroll
        for (int rg = 0; rg < 16; ++rg) {
            const int rl = (rg & 3) + 8 * (rg >> 2) + 4 * g;
            float s0 = acc0[rg], s1 = acc1[rg];
            #pragma unroll
            for (int j = 0; j < 7; ++j) {
                s0 += red_s[j][cw][rl * 64 + c31];
                s1 += red_s[j][cw][rl * 64 + 32 + c31];
            }
            const float inv = 1.0f / S_s[rl];
            const int row = b0 + rl;
            const int colA = cw * 64 + c31;
            const int colB = colA + 32;
            out[(size_t)row * D_TOT + colA] = patient[(size_t)row * D_TOT + colA] + s0 * inv;
            out[(size_t)row * D_TOT + colB] = patient[(size_t)row * D_TOT + colB] + s1 * inv;
        }
    }
}

// ---------------- tiny fallback (round-1, known-passing) ----------------
__global__ __launch_bounds__(256) void pq_fb(const float* __restrict__ patient,
                                             const float* __restrict__ disease,
                                             const float* __restrict__ ak,
                                             float* __restrict__ p,
                                             float* __restrict__ q) {
    int gid  = blockIdx.x * blockDim.x + threadIdx.x;
    int wid  = gid >> 6;
    int lane = gid & 63;
    const float* src;
    const float* a;
    float* dst;
    if (wid < B_TOT) {
        src = patient + (size_t)wid * D_TOT; a = ak; dst = p + wid;
    } else {
        src = disease + (size_t)(wid - B_TOT) * D_TOT; a = ak + D_TOT; dst = q + (wid - B_TOT);
    }
    float s = src[lane] * a[lane] + src[lane + 64] * a[lane + 64];
    #pragma unroll
    for (int off = 32; off; off >>= 1) s += __shfl_xor(s, off);
    if (lane == 0) *dst = s;
}

#define FBP 16
#define FNT 256
__global__ __launch_bounds__(256) void gat_fb(const float* __restrict__ patient,
                                              const float* __restrict__ disease,
                                              const float* __restrict__ p,
                                              const float* __restrict__ q,
                                              float* __restrict__ out) {
    __shared__ float q_s[N_TOT];
    __shared__ float w_s[FBP][FNT];
    __shared__ float m_s[FBP], S_s[FBP], pp_s[FBP];
    const int tid = threadIdx.x;
    const int b0  = blockIdx.x * FBP;
    for (int i = tid; i < N_TOT; i += 256) q_s[i] = q[i];
    if (tid < FBP) pp_s[tid] = p[b0 + tid];
    __syncthreads();
    const int wave = tid >> 6, lane = tid & 63;
    for (int pi = wave * 4; pi < wave * 4 + 4; ++pi) {
        float pp = pp_s[pi];
        float mx = -1e30f;
        for (int n = lane; n < N_TOT; n += 64) {
            float x = pp + q_s[n]; x = x > 0.0f ? x : LEAKY * x; mx = fmaxf(mx, x);
        }
        #pragma unroll
        for (int off = 32; off; off >>= 1) mx = fmaxf(mx, __shfl_xor(mx, off));
        float sum = 0.0f;
        for (int n = lane; n < N_TOT; n += 64) {
            float x = pp + q_s[n]; x = x > 0.0f ? x : LEAKY * x; sum += __expf(x - mx);
        }
        #pragma unroll
        for (int off = 32; off; off >>= 1) sum += __shfl_xor(sum, off);
        if (lane == 0) { m_s[pi] = mx; S_s[pi] = sum; }
    }
    __syncthreads();
    const int d2 = tid & 31;
    const int pg = tid >> 5;
    const int p0 = 2 * pg, p1 = 2 * pg + 1;
    float4 acc0 = make_float4(0.f, 0.f, 0.f, 0.f);
    float4 acc1 = make_float4(0.f, 0.f, 0.f, 0.f);
    for (int n0 = 0; n0 < N_TOT; n0 += FNT) {
        __syncthreads();
        for (int i = tid; i < FBP * FNT; i += 256) {
            int pi = i >> 8;
            int nt = i & (FNT - 1);
            float x = pp_s[pi] + q_s[n0 + nt];
            x = x > 0.0f ? x : LEAKY * x;
            w_s[pi][nt] = __expf(x - m_s[pi]);
        }
        __syncthreads();
        const float* drow = disease + (size_t)n0 * D_TOT + d2 * 4;
        #pragma unroll 4
        for (int nt = 0; nt < FNT; ++nt) {
            float4 dv = *reinterpret_cast<const float4*>(drow + (size_t)nt * D_TOT);
            float w0 = w_s[p0][nt];
            float w1 = w_s[p1][nt];
            acc0.x += w0 * dv.x; acc0.y += w0 * dv.y; acc0.z += w0 * dv.z; acc0.w += w0 * dv.w;
            acc1.x += w1 * dv.x; acc1.y += w1 * dv.y; acc1.z += w1 * dv.z; acc1.w += w1 * dv.w;
        }
    }
    const float inv0 = 1.0f / S_s[p0];
    const float inv1 = 1.0f / S_s[p1];
    {
        size_t off = (size_t)(b0 + p0) * D_TOT + d2 * 4;
        float4 pf = *reinterpret_cast<const float4*>(patient + off);
        float4 o;
        o.x = pf.x + acc0.x * inv0; o.y = pf.y + acc0.y * inv0;
        o.z = pf.z + acc0.z * inv0; o.w = pf.w + acc0.w * inv0;
        *reinterpret_cast<float4*>(reinterpret_cast<float*>(out) + off) = o;
    }
    {
        size_t off = (size_t)(b0 + p1) * D_TOT + d2 * 4;
        float4 pf = *reinterpret_cast<const float4*>(patient + off);
        float4 o;
        o.x = pf.x + acc1.x * inv1; o.y = pf.y + acc1.y * inv1;
        o.z = pf.z + acc1.z * inv1; o.w = pf.w + acc1.w * inv1;
        *reinterpret_cast<float4*>(reinterpret_cast<float*>(out) + off) = o;
    }
}

extern "C" void kernel_launch(void* const* d_in, const int* in_sizes, int n_in,
                              void* d_out, int out_size, void* d_ws, size_t ws_size,
                              hipStream_t stream) {
    const float* patient = (const float*)d_in[0];   // 8192 x 128
    const float* disease = (const float*)d_in[1];   // 2048 x 128
    const float* ak      = (const float*)d_in[2];   // 256
    float* out = (float*)d_out;

    const size_t need_fast = (size_t)512 * 1024 + 8192;   // DnTf (512KB) + q (8KB)
    if (ws_size >= need_fast) {
        uint4* DnTf = (uint4*)d_ws;                          // 128 kt x 4 ct x 64 uint4 = 512KB
        float* q    = (float*)((char*)d_ws + 512 * 1024);    // 2048 f32
        prep_kernel<<<N_TOT / 32, 256, 0, stream>>>(disease, ak, q, DnTf);
        gat_mfma32<<<B_TOT / BM, 1024, 0, stream>>>(patient, ak, q, DnTf, out);
    } else {
        float* p = (float*)d_ws;          // 8192 f32
        float* q = p + B_TOT;             // 2048 f32
        pq_fb<<<(B_TOT + N_TOT) / 4, 256, 0, stream>>>(patient, disease, ak, p, q);
        gat_fb<<<B_TOT / FBP, 256, 0, stream>>>(patient, disease, p, q, out);
    }
}